// Round 10
// baseline (20991.429 us; speedup 1.0000x reference)
//
#include <hip/hip_runtime.h>

// ---------------------------------------------------------------------------
// Persistent seq2seq LSTM, v10 = v9 with FORCED pipelined GEMM.
// gg_force: chunked double-buffered A prefetch pinned by sched_barrier(0)
// so the compiler cannot sink loads to their use sites (v9's VGPR=64 proved
// it did exactly that). >=8 loads in flight per wave; all chunk indices are
// compile-time (full unroll) so the frag arrays stay in registers.
// Everything else identical to v9: 256 blocks x 1024 threads, block p owns
// 16 gate cols (full K=1536, gates complete in-block, c in regs); x in
// 4-slot fragment ring; h in 2 planes; UC flag stores + hierarchical polls;
// one acquire fence per block per step at the h-wait; decoder fc on blocks
// 128..255, softmax+y on 0..127.
// ---------------------------------------------------------------------------

#define TS 384

typedef __attribute__((ext_vector_type(8))) short bf16x8;
typedef __attribute__((ext_vector_type(4))) float f32x4;

// ws layout
#define WS_XR 4096u                      // x ring: 4 slots x (hi 128KB + lo 128KB)
#define XR_SLOT 262144u
#define WS_HP (WS_XR + 4u*XR_SLOT)       // h planes: 2 bufs x (hi 256KB + lo 256KB)
#define HP_BUF 524288u
#define WS_FPN (WS_HP + 2u*HP_BUF)       // fc partials 8*128*512*4 = 2MB
#define WS_TOTAL (WS_FPN + 2097152u)

#define MFMA __builtin_amdgcn_mfma_f32_16x16x32_bf16

__device__ __forceinline__ unsigned short bf16r(float v) {
  unsigned u = __float_as_uint(v);
  u += 0x7FFFu + ((u >> 16) & 1u);
  return (unsigned short)(u >> 16);
}
__device__ __forceinline__ float bf2f(unsigned short h) {
  return __uint_as_float(((unsigned)h) << 16);
}
__device__ __forceinline__ void split2(float v, short& hi, short& lo) {
  unsigned short h = bf16r(v);
  float r = v - bf2f(h);
  hi = (short)h; lo = (short)bf16r(r);
}
__device__ __forceinline__ float sigm(float v)  { return 1.0f / (1.0f + __expf(-v)); }
__device__ __forceinline__ float tanhfa(float v){ return 1.0f - 2.0f / (__expf(2.0f*v) + 1.0f); }

__device__ __forceinline__ void st_u64(void* p, unsigned long long v) {
  __hip_atomic_store((unsigned long long*)p, v, __ATOMIC_RELAXED, __HIP_MEMORY_SCOPE_AGENT);
}
__device__ __forceinline__ unsigned long long ld_u64(const void* p) {
  return __hip_atomic_load((const unsigned long long*)p, __ATOMIC_RELAXED, __HIP_MEMORY_SCOPE_AGENT);
}
__device__ __forceinline__ void st_u32(unsigned* p, unsigned v) {
  __hip_atomic_store(p, v, __ATOMIC_RELAXED, __HIP_MEMORY_SCOPE_AGENT);
}
__device__ __forceinline__ void st_f32(float* p, float v) {
  __hip_atomic_store(p, v, __ATOMIC_RELAXED, __HIP_MEMORY_SCOPE_AGENT);
}
__device__ __forceinline__ float ld_f32(const float* p) {
  return __hip_atomic_load(p, __ATOMIC_RELAXED, __HIP_MEMORY_SCOPE_AGENT);
}
union FRAG { unsigned long long q[2]; bf16x8 v; };
__device__ __forceinline__ bf16x8 ld_frag(const short* base) {
  FRAG u;
  u.q[0] = ld_u64(base);
  u.q[1] = ld_u64(base + 4);
  return u.v;
}

// ---- sync primitives --------------------------------------------------------
__device__ __forceinline__ void setflag(unsigned* flag, unsigned val) {
  asm volatile("s_waitcnt vmcnt(0)" ::: "memory");
  __syncthreads();
  if (threadIdx.x == 0)
    __hip_atomic_store(flag, val, __ATOMIC_RELAXED, __HIP_MEMORY_SCOPE_AGENT);
}
__device__ __forceinline__ void wait_hier(const unsigned* flags, unsigned* pub,
    int aggIdx, int nPub, unsigned target, bool fence, int* sDead) {
  const int t = threadIdx.x;
  if (aggIdx >= 0) {
    if (t < 8) {
      const unsigned long long* q = (const unsigned long long*)(flags + aggIdx * 32 + t * 4);
      unsigned spins = 0;
      for (;;) {
        unsigned long long q0 = ld_u64(q), q1 = ld_u64(q + 1);
        bool ok = ((unsigned)q0 >= target) && ((unsigned)(q0 >> 32) >= target)
               && ((unsigned)q1 >= target) && ((unsigned)(q1 >> 32) >= target);
        if (__all(ok)) break;
        __builtin_amdgcn_s_sleep(1);
        if (++spins > (1u << 19)) { if (t == 0) *sDead = 1; break; }
      }
    }
    if (t == 0) st_u32(&pub[aggIdx], target);
  }
  if (t == 0) {
    unsigned spins = 0;
    for (;;) {
      bool ok = true;
      #pragma unroll
      for (int i = 0; i < 4; ++i) {
        if (i * 2 < nPub) {
          unsigned long long q0 = ld_u64((const unsigned long long*)pub + i);
          if (!((unsigned)q0 >= target && (unsigned)(q0 >> 32) >= target)) ok = false;
        }
      }
      if (ok) break;
      __builtin_amdgcn_s_sleep(1);
      if (++spins > (1u << 19)) { *sDead = 1; break; }
    }
    if (fence) __builtin_amdgcn_fence(__ATOMIC_ACQUIRE, "agent");
  }
  __syncthreads();
}
__device__ __forceinline__ void wait64(const unsigned* flags, unsigned target, int* sDead) {
  if (threadIdx.x < 16) {
    const unsigned long long* q = (const unsigned long long*)(flags + threadIdx.x * 4);
    unsigned spins = 0;
    for (;;) {
      unsigned long long q0 = ld_u64(q), q1 = ld_u64(q + 1);
      bool ok = ((unsigned)q0 >= target) && ((unsigned)(q0 >> 32) >= target)
             && ((unsigned)q1 >= target) && ((unsigned)(q1 >> 32) >= target);
      if (__all(ok)) break;
      __builtin_amdgcn_s_sleep(1);
      if (++spins > (1u << 19)) { if (threadIdx.x == 0) *sDead = 1; break; }
    }
  }
  __syncthreads();
}

// ---- weight loaders --------------------------------------------------------
__device__ void load_gate_weights(const float* __restrict__ Wx, const float* __restrict__ Wh,
                                  int p, short* sBh, short* sBl) {
  for (int idx = threadIdx.x; idx < 24576; idx += 1024) {
    int j = idx & 7, l = (idx >> 3) & 63, kb = idx >> 9;
    int k = kb * 32 + ((l >> 4) << 3) + j;
    int c = l & 15;
    int gcol = (c >> 2) * 1024 + p * 4 + (c & 3);
    float wv = (k < 512) ? Wx[(size_t)k * 4096 + gcol]
                         : Wh[(size_t)(k - 512) * 4096 + gcol];
    short hi, lo; split2(wv, hi, lo);
    sBh[idx] = hi; sBl[idx] = lo;
  }
}
__device__ void load_fc_weights(const float* __restrict__ fcW, int kg, int cg,
                                short* sFh, short* sFl) {
  for (int idx = threadIdx.x; idx < 4096; idx += 1024) {
    int j = idx & 7, l = (idx >> 3) & 63, kb = idx >> 9;
    int unit = kg * 256 + kb * 32 + ((l >> 4) << 3) + j;
    int col = cg * 16 + (l & 15);
    short hi, lo; split2(fcW[(size_t)unit * 512 + col], hi, lo);
    sFh[idx] = hi; sFl[idx] = lo;
  }
}

// ---- FORCED pipelined gate GEMM: chunked dbuf + sched_barrier pinning ------
template<int NKB>
__device__ __forceinline__ void gg_force(const short* AH_, const short* AL_,
    const short* BH_, const short* BL_, int mt, int l,
    int kbA0, int kbB0, f32x4* acc)
{
  const bf16x8* AH = (const bf16x8*)AH_;
  const bf16x8* AL = (const bf16x8*)AL_;
  const bf16x8* BH = (const bf16x8*)BH_;
  const bf16x8* BL = (const bf16x8*)BL_;
  constexpr int CH = 4;                    // kbs per chunk
  constexpr int NC = NKB / CH;             // 2 (x-part) or 4 (h-part)
  bf16x8 ah[2][CH], al[2][CH];
  #pragma unroll
  for (int i = 0; i < CH; ++i) {           // prologue: chunk 0 loads
    ah[0][i] = AH[((kbA0 + i) * 8 + mt) * 64 + l];
    al[0][i] = AL[((kbA0 + i) * 8 + mt) * 64 + l];
  }
  __builtin_amdgcn_sched_barrier(0);       // pin: prologue loads issued here
  #pragma unroll
  for (int c = 0; c < NC; ++c) {
    constexpr int dummy = 0; (void)dummy;
    const int cur = c & 1, nxt = cur ^ 1;  // compile-time after unroll
    if (c + 1 < NC) {
      #pragma unroll
      for (int i = 0; i < CH; ++i) {
        int kb = kbA0 + (c + 1) * CH + i;
        ah[nxt][i] = AH[(kb * 8 + mt) * 64 + l];
        al[nxt][i] = AL[(kb * 8 + mt) * 64 + l];
      }
    }
    __builtin_amdgcn_sched_barrier(0);     // loads of c+1 cannot sink below
    #pragma unroll
    for (int i = 0; i < CH; ++i) {
      int kbl = kbB0 + c * CH + i;
      bf16x8 bh = BH[kbl * 64 + l];
      bf16x8 bl = BL[kbl * 64 + l];
      const int a = (i & 1) * 3;
      acc[a + 0] = MFMA(ah[cur][i], bh, acc[a + 0], 0, 0, 0);
      acc[a + 1] = MFMA(ah[cur][i], bl, acc[a + 1], 0, 0, 0);
      acc[a + 2] = MFMA(al[cur][i], bh, acc[a + 2], 0, 0, 0);
    }
    __builtin_amdgcn_sched_barrier(0);     // MFMAs of c cannot sink below
  }
}
__device__ __forceinline__ void gg_finish(f32x4* acc, int kh, int mt, int l,
                                          float* LDSgate) {
  f32x4 s = (acc[0] + acc[3]) + ((acc[1] + acc[4]) + (acc[2] + acc[5]));
  const int col = l & 15, r0 = mt * 16 + ((l >> 4) << 2);
  float* plane = LDSgate + kh * 2176;
  #pragma unroll
  for (int j = 0; j < 4; ++j) plane[(r0 + j) * 17 + col] = s[j];
}

// ---- x conversion into fragment-ordered x-ring slot ------------------------
__device__ __forceinline__ void conv_x(const float* __restrict__ xsrc,
                                       short* dstH, short* dstL, int p, int tl) {
  if (tl < 32) {
    int g = p * 32 + tl;                      // 0..8191
    int l = g & 63, mt = (g >> 6) & 7, kb = g >> 9;
    int row = mt * 16 + (l & 15), k = kb * 32 + ((l >> 4) << 3);
    const float* xs = xsrc + (size_t)row * 512 + k;
    unsigned long long h64[2] = {0, 0}, l64[2] = {0, 0};
    #pragma unroll
    for (int j = 0; j < 8; ++j) {
      short hi, lo; split2(xs[j], hi, lo);
      h64[j >> 2] |= (unsigned long long)(unsigned short)hi << ((j & 3) * 16);
      l64[j >> 2] |= (unsigned long long)(unsigned short)lo << ((j & 3) * 16);
    }
    int off = g * 8;
    st_u64(dstH + off, h64[0]); st_u64(dstH + off + 4, h64[1]);
    st_u64(dstL + off, l64[0]); st_u64(dstL + off + 4, l64[1]);
  }
}

__global__ void __launch_bounds__(1024, 1)
lstm10(const float* __restrict__ x, const float* __restrict__ h0p,
       const float* __restrict__ c0p, const float* __restrict__ eWx,
       const float* __restrict__ eWh, const float* __restrict__ eb,
       const float* __restrict__ dWx, const float* __restrict__ dWh,
       const float* __restrict__ db, const float* __restrict__ fcW,
       const float* __restrict__ fcb, float* __restrict__ out,
       char* __restrict__ ws)
{
  __shared__ __align__(16) short sBh[24576], sBl[24576];   // 96 KB
  __shared__ __align__(16) short sFh[4096], sFl[4096];     // 16 KB
  __shared__ float LDSgate[2 * 2176];                      // 17.4 KB
  __shared__ unsigned hsplit[512];
  __shared__ float ybuf[512];
  __shared__ float red[16];
  __shared__ int sDead;

  const int p = blockIdx.x, t = threadIdx.x;
  const int w = t >> 6, l = t & 63;
  const int mt = w & 7, kh = w >> 3;
  if (t == 0) sDead = 0;

  unsigned* hflag = (unsigned*)ws;                 // 256 flags
  unsigned* yflag = (unsigned*)(ws + 1024);        // 128 flags
  unsigned* fflag = (unsigned*)(ws + 2048);        // 128 flags
  unsigned* hpub  = (unsigned*)(ws + 3072);        // 8 epochs (one line)
  unsigned* ypub  = (unsigned*)(ws + 3200);        // 4 epochs
  unsigned* fpub  = (unsigned*)(ws + 3328);        // 4 epochs

  const int hagg = (p < 8) ? p : -1;
  const int yagg = (p >= 8 && p < 12) ? p - 8 : -1;
  const int fagg = (p >= 12 && p < 16) ? p - 12 : -1;

  short* xrH[4]; short* xrL[4];
  #pragma unroll
  for (int s4 = 0; s4 < 4; ++s4) {
    xrH[s4] = (short*)(ws + WS_XR + s4 * XR_SLOT);
    xrL[s4] = (short*)(ws + WS_XR + s4 * XR_SLOT + 131072u);
  }
  short* hpH[2]; short* hpL[2];
  #pragma unroll
  for (int b2 = 0; b2 < 2; ++b2) {
    hpH[b2] = (short*)(ws + WS_HP + b2 * HP_BUF);
    hpL[b2] = (short*)(ws + WS_HP + b2 * HP_BUF + 262144u);
  }
  float* fp = (float*)(ws + WS_FPN);

  const int row_pw = t & 127, u_pw = (t >> 7) & 3;

  // ================= init =================
  load_gate_weights(eWx, eWh, p, sBh, sBl);
  conv_x(x, xrH[0], xrL[0], p, t);                       // x(0)
  conv_x(x + 65536, xrH[1], xrL[1], p, t);               // x(1)
  if (t < 64) {                                          // h0 -> hp[0]
    int hg = p * 64 + t;
    int ll = hg & 63, mtt = (hg >> 6) & 7, hk = hg >> 9;
    int row = mtt * 16 + (ll & 15), k = hk * 32 + ((ll >> 4) << 3);
    const float* hs = h0p + (size_t)row * 1024 + k;
    unsigned long long h64[2] = {0, 0}, l64[2] = {0, 0};
    #pragma unroll
    for (int j = 0; j < 8; ++j) {
      short hi, lo; split2(hs[j], hi, lo);
      h64[j >> 2] |= (unsigned long long)(unsigned short)hi << ((j & 3) * 16);
      l64[j >> 2] |= (unsigned long long)(unsigned short)lo << ((j & 3) * 16);
    }
    int off = hg * 8;
    st_u64(hpH[0] + off, h64[0]); st_u64(hpH[0] + off + 4, h64[1]);
    st_u64(hpL[0] + off, l64[0]); st_u64(hpL[0] + off + 4, l64[1]);
  }
  float creg = 0.f, bq0 = 0.f, bq1 = 0.f, bq2 = 0.f, bq3 = 0.f;
  if (t < 512) {
    creg = c0p[(size_t)row_pw * 1024 + p * 4 + u_pw];
    bq0 = eb[0 * 1024 + p * 4 + u_pw];
    bq1 = eb[1 * 1024 + p * 4 + u_pw];
    bq2 = eb[2 * 1024 + p * 4 + u_pw];
    bq3 = eb[3 * 1024 + p * 4 + u_pw];
  }
  setflag(&hflag[p], 1u);
  wait_hier(hflag, hpub, hagg, 8, 1u, true, &sDead);     // init barrier
  if (sDead) return;

  // ================= encoder =================
  for (int st = 0; st < TS; ++st) {
    int rb = st & 1, wb = rb ^ 1, xs = st & 3;
    f32x4 z = {0.f, 0.f, 0.f, 0.f};
    f32x4 acc[6] = {z, z, z, z, z, z};
    // x-part BEFORE the wait
    gg_force<8>(xrH[xs], xrL[xs], sBh, sBl, mt, l, kh * 8, kh * 8, acc);
    wait_hier(hflag, hpub, hagg, 8, (unsigned)(st + 1), true, &sDead);  // one fence/step
    if (sDead) return;
    gg_force<16>(hpH[rb], hpL[rb], sBh, sBl, mt, l, kh * 16, 16 + kh * 16, acc);
    gg_finish(acc, kh, mt, l, LDSgate);
    __syncthreads();
    if (t < 512) {
      float g0 = LDSgate[row_pw * 17 + 0  + u_pw] + LDSgate[2176 + row_pw * 17 + 0  + u_pw] + bq0;
      float g1 = LDSgate[row_pw * 17 + 4  + u_pw] + LDSgate[2176 + row_pw * 17 + 4  + u_pw] + bq1;
      float g2 = LDSgate[row_pw * 17 + 8  + u_pw] + LDSgate[2176 + row_pw * 17 + 8  + u_pw] + bq2;
      float g3 = LDSgate[row_pw * 17 + 12 + u_pw] + LDSgate[2176 + row_pw * 17 + 12 + u_pw] + bq3;
      creg = sigm(g1) * creg + sigm(g0) * tanhfa(g2);
      float h = sigm(g3) * tanhfa(creg);
      short hi, lo; split2(h, hi, lo);
      hsplit[u_pw * 128 + row_pw] = ((unsigned)(unsigned short)hi << 16) | (unsigned short)lo;
    } else if (st + 2 < TS) {
      conv_x(x + (size_t)(st + 2) * 65536, xrH[(st + 2) & 3], xrL[(st + 2) & 3], p, t - 512);
    }
    __syncthreads();
    if (t < 128) {                                       // pack h slice (4 units)
      int r = t;
      unsigned w0 = hsplit[r], w1 = hsplit[128 + r], w2 = hsplit[256 + r], w3 = hsplit[384 + r];
      unsigned long long hi64 = (unsigned long long)(w0 >> 16)
        | ((unsigned long long)(w1 >> 16) << 16)
        | ((unsigned long long)(w2 >> 16) << 32)
        | ((unsigned long long)(w3 >> 16) << 48);
      unsigned long long lo64 = (unsigned long long)(w0 & 0xFFFFu)
        | ((unsigned long long)(w1 & 0xFFFFu) << 16)
        | ((unsigned long long)(w2 & 0xFFFFu) << 32)
        | ((unsigned long long)(w3 & 0xFFFFu) << 48);
      int hk = p >> 3, mtt = r >> 4;
      int lane_ = (((p >> 1) & 3) << 4) | (r & 15);
      int off = ((hk * 8 + mtt) * 64 + lane_) * 8 + (p & 1) * 4;
      st_u64(hpH[wb] + off, hi64);
      st_u64(hpL[wb] + off, lo64);
    }
    setflag(&hflag[p], (unsigned)(st + 2));
  }

  // ================= switch to decoder =================
  load_gate_weights(dWx, dWh, p, sBh, sBl);
  if (p >= 128) load_fc_weights(fcW, (p - 128) >> 5, (p - 128) & 31, sFh, sFl);
  if (t < 32) {                                          // zero y0 (slot 0)
    int off = (p * 32 + t) * 8;
    st_u64(xrH[0] + off, 0ull); st_u64(xrH[0] + off + 4, 0ull);
    st_u64(xrL[0] + off, 0ull); st_u64(xrL[0] + off + 4, 0ull);
  }
  creg = 0.0f;
  if (t < 512) {
    bq0 = db[0 * 1024 + p * 4 + u_pw];
    bq1 = db[1 * 1024 + p * 4 + u_pw];
    bq2 = db[2 * 1024 + p * 4 + u_pw];
    bq3 = db[3 * 1024 + p * 4 + u_pw];
  }
  float fcb_r = (t < 512) ? fcb[t] : 0.f;
  setflag(&hflag[p], (unsigned)(TS + 2));

  // ================= decoder =================
  const unsigned DB = (unsigned)(TS + 2);
  for (int st = 0; st < TS; ++st) {
    int rb = st & 1, wb = rb ^ 1;
    int ys = st & 1, yw = ys ^ 1;
    f32x4 z = {0.f, 0.f, 0.f, 0.f};
    f32x4 acc[6] = {z, z, z, z, z, z};
    wait_hier(hflag, hpub, hagg, 8, DB + (unsigned)st, true, &sDead);   // one fence/step
    if (sDead) return;
    gg_force<16>(hpH[rb], hpL[rb], sBh, sBl, mt, l, kh * 16, 16 + kh * 16, acc);
    wait_hier(yflag, ypub, yagg, 4, (unsigned)st, false, &sDead);       // y(st-1)
    if (sDead) return;
    gg_force<8>(xrH[ys], xrL[ys], sBh, sBl, mt, l, kh * 8, kh * 8, acc);
    gg_finish(acc, kh, mt, l, LDSgate);
    __syncthreads();
    if (t < 512) {
      float g0 = LDSgate[row_pw * 17 + 0  + u_pw] + LDSgate[2176 + row_pw * 17 + 0  + u_pw] + bq0;
      float g1 = LDSgate[row_pw * 17 + 4  + u_pw] + LDSgate[2176 + row_pw * 17 + 4  + u_pw] + bq1;
      float g2 = LDSgate[row_pw * 17 + 8  + u_pw] + LDSgate[2176 + row_pw * 17 + 8  + u_pw] + bq2;
      float g3 = LDSgate[row_pw * 17 + 12 + u_pw] + LDSgate[2176 + row_pw * 17 + 12 + u_pw] + bq3;
      creg = sigm(g1) * creg + sigm(g0) * tanhfa(g2);
      float h = sigm(g3) * tanhfa(creg);
      short hi, lo; split2(h, hi, lo);
      hsplit[u_pw * 128 + row_pw] = ((unsigned)(unsigned short)hi << 16) | (unsigned short)lo;
    }
    __syncthreads();
    if (t < 128) {
      int r = t;
      unsigned w0 = hsplit[r], w1 = hsplit[128 + r], w2 = hsplit[256 + r], w3 = hsplit[384 + r];
      unsigned long long hi64 = (unsigned long long)(w0 >> 16)
        | ((unsigned long long)(w1 >> 16) << 16)
        | ((unsigned long long)(w2 >> 16) << 32)
        | ((unsigned long long)(w3 >> 16) << 48);
      unsigned long long lo64 = (unsigned long long)(w0 & 0xFFFFu)
        | ((unsigned long long)(w1 & 0xFFFFu) << 16)
        | ((unsigned long long)(w2 & 0xFFFFu) << 32)
        | ((unsigned long long)(w3 & 0xFFFFu) << 48);
      int hk = p >> 3, mtt = r >> 4;
      int lane_ = (((p >> 1) & 3) << 4) | (r & 15);
      int off = ((hk * 8 + mtt) * 64 + lane_) * 8 + (p & 1) * 4;
      st_u64(hpH[wb] + off, hi64);
      st_u64(hpL[wb] + off, lo64);
    }
    setflag(&hflag[p], DB + (unsigned)(st + 1));          // h(st) ready

    if (p >= 128) {
      // ---- fc GEMM on blocks 128..255 (UC hp reads, preloaded) ----
      const int f = p - 128, kg = f >> 5, cg = f & 31;
      wait64(hflag + kg * 64, DB + (unsigned)(st + 1), &sDead);
      if (sDead) return;
      {
        const bf16x8* FB = (const bf16x8*)sFh;
        const bf16x8* FL = (const bf16x8*)sFl;
        bf16x8 fah[4], fal[4];
        #pragma unroll
        for (int kb = 0; kb < 4; ++kb) {
          int gkb = kg * 8 + kh * 4 + kb;
          fah[kb] = ld_frag(hpH[wb] + ((gkb * 8 + mt) * 64 + l) * 8);
          fal[kb] = ld_frag(hpL[wb] + ((gkb * 8 + mt) * 64 + l) * 8);
        }
        __builtin_amdgcn_sched_barrier(0);
        f32x4 a0 = z, a1 = z, a2 = z;
        #pragma unroll
        for (int kb = 0; kb < 4; ++kb) {
          bf16x8 bh = FB[(kh * 4 + kb) * 64 + l];
          bf16x8 bl = FL[(kh * 4 + kb) * 64 + l];
          a0 = MFMA(fah[kb], bh, a0, 0, 0, 0);
          a1 = MFMA(fah[kb], bl, a1, 0, 0, 0);
          a2 = MFMA(fal[kb], bh, a2, 0, 0, 0);
        }
        f32x4 s = a0 + (a1 + a2);
        int slice = kg * 2 + kh;
        int col = cg * 16 + (l & 15), r0 = mt * 16 + ((l >> 4) << 2);
        #pragma unroll
        for (int j = 0; j < 4; ++j)
          st_f32(&fp[(size_t)(slice * 128 + r0 + j) * 512 + col], s[j]);
      }
      setflag(&fflag[f], (unsigned)(st + 1));
    } else {
      // ---- softmax + y-pack on blocks 0..127 (UC fp reads, preloaded) ----
      wait_hier(fflag, fpub, fagg, 4, (unsigned)(st + 1), false, &sDead);
      if (sDead) return;
      float v = 0.f, e = 0.f, mx;
      if (t < 512) {
        float tv[8];
        #pragma unroll
        for (int s8 = 0; s8 < 8; ++s8)
          tv[s8] = ld_f32(&fp[(size_t)(s8 * 128 + p) * 512 + t]);
        v = fcb_r + ((tv[0] + tv[1]) + (tv[2] + tv[3]))
                  + ((tv[4] + tv[5]) + (tv[6] + tv[7]));
        mx = v;
        #pragma unroll
        for (int o = 32; o > 0; o >>= 1) mx = fmaxf(mx, __shfl_xor(mx, o));
        if (l == 0) red[w] = mx;
      }
      __syncthreads();
      if (t < 512) {
        mx = red[0];
        #pragma unroll
        for (int i = 1; i < 8; ++i) mx = fmaxf(mx, red[i]);
        e = __expf(v - mx);
        float ss = e;
        #pragma unroll
        for (int o = 32; o > 0; o >>= 1) ss += __shfl_xor(ss, o);
        if (l == 0) red[8 + w] = ss;
      }
      __syncthreads();
      if (t < 512) {
        float ss = (red[8] + red[9]) + (red[10] + red[11])
                 + (red[12] + red[13]) + (red[14] + red[15]);
        float y = e / ss;
        out[((size_t)st * 128 + p) * 512 + t] = y;
        ybuf[t] = y;
      }
      __syncthreads();
      if (t < 64) {                                      // pack y row p
        int kb = t >> 2, seg = t & 3;
        int k = kb * 32 + seg * 8;
        int lane_ = (seg << 4) | (p & 15), mtt = p >> 4;
        int off = ((kb * 8 + mtt) * 64 + lane_) * 8;
        unsigned long long h64[2] = {0, 0}, l64[2] = {0, 0};
        #pragma unroll
        for (int j = 0; j < 8; ++j) {
          short hi, lo; split2(ybuf[k + j], hi, lo);
          h64[j >> 2] |= (unsigned long long)(unsigned short)hi << ((j & 3) * 16);
          l64[j >> 2] |= (unsigned long long)(unsigned short)lo << ((j & 3) * 16);
        }
        st_u64(xrH[yw] + off, h64[0]); st_u64(xrH[yw] + off + 4, h64[1]);
        st_u64(xrL[yw] + off, l64[0]); st_u64(xrL[yw] + off + 4, l64[1]);
      }
      setflag(&yflag[p], (unsigned)(st + 1));
    }
  }
}

extern "C" void kernel_launch(void* const* d_in, const int* in_sizes, int n_in,
                              void* d_out, int out_size, void* d_ws, size_t ws_size,
                              hipStream_t stream) {
  const float* x   = (const float*)d_in[0];
  const float* h0  = (const float*)d_in[1];
  const float* c0  = (const float*)d_in[2];
  const float* eWx = (const float*)d_in[3];
  const float* eWh = (const float*)d_in[4];
  const float* eb  = (const float*)d_in[5];
  const float* dWx = (const float*)d_in[6];
  const float* dWh = (const float*)d_in[7];
  const float* db  = (const float*)d_in[8];
  const float* fcW = (const float*)d_in[9];
  const float* fcb = (const float*)d_in[10];
  float* out = (float*)d_out;

  if (ws_size < (size_t)WS_TOTAL) {
    hipMemsetAsync(d_out, 0xFF, (size_t)out_size * sizeof(float), stream);
    return;
  }
  hipMemsetAsync(d_ws, 0, 4096, stream);   // flags + pubs
  hipLaunchKernelGGL(lstm10, dim3(256), dim3(1024), 0, stream,
                     x, h0, c0, eWx, eWh, eb, dWx, dWh, db, fcW, fcb, out,
                     (char*)d_ws);
}

// Round 11
// 15129.288 us; speedup vs baseline: 1.3875x; 1.3875x over previous
//
#include <hip/hip_runtime.h>

// ---------------------------------------------------------------------------
// Persistent seq2seq LSTM, v11 = v9 + per-XCD leader invalidation.
// Mechanism fix: v4-v10 executed one agent-acquire (full L2 inv) PER BLOCK
// per step = 32 invs/XCD/step -> A-operand reads never hit L2; served by LLC
// at ~600cy with ~2 loads in flight = the ~80% stall. v11 elects one leader
// block per XCD (HW_REG_XCC_ID + one-time atomic election). Per step: leader
// polls all 256 h-flags, does THE single agent fence (L2+L1 inv), publishes
// invdone[xcd]=epoch (UC). Other blocks poll invdone only, then L1-only inv
// (buffer_inv sc0) and read CACHED -> L2-served. Freshness: UC payload writes
// land in LLC before flags; after the leader inv no stale line can re-enter
// L2 (LLC is fresh); y/x/fp keep the no-retouch/UC arguments. out stores are
// now UC so no dirty L2 lines exist (invs can't lose data).
// Everything else identical to v9 (structure, flags, GEMM, decoder chain).
// ---------------------------------------------------------------------------

#define TS 384

typedef __attribute__((ext_vector_type(8))) short bf16x8;
typedef __attribute__((ext_vector_type(4))) float f32x4;

// ws layout
#define WS_XR 4096u                      // x ring: 4 slots x (hi 128KB + lo 128KB)
#define XR_SLOT 262144u
#define WS_HP (WS_XR + 4u*XR_SLOT)       // h planes: 2 bufs x (hi 256KB + lo 256KB)
#define HP_BUF 524288u
#define WS_FPN (WS_HP + 2u*HP_BUF)       // fc partials 8*128*512*4 = 2MB
#define WS_TOTAL (WS_FPN + 2097152u)

#define MFMA __builtin_amdgcn_mfma_f32_16x16x32_bf16

__device__ __forceinline__ unsigned short bf16r(float v) {
  unsigned u = __float_as_uint(v);
  u += 0x7FFFu + ((u >> 16) & 1u);
  return (unsigned short)(u >> 16);
}
__device__ __forceinline__ float bf2f(unsigned short h) {
  return __uint_as_float(((unsigned)h) << 16);
}
__device__ __forceinline__ void split2(float v, short& hi, short& lo) {
  unsigned short h = bf16r(v);
  float r = v - bf2f(h);
  hi = (short)h; lo = (short)bf16r(r);
}
__device__ __forceinline__ float sigm(float v)  { return 1.0f / (1.0f + __expf(-v)); }
__device__ __forceinline__ float tanhfa(float v){ return 1.0f - 2.0f / (__expf(2.0f*v) + 1.0f); }

__device__ __forceinline__ void st_u64(void* p, unsigned long long v) {
  __hip_atomic_store((unsigned long long*)p, v, __ATOMIC_RELAXED, __HIP_MEMORY_SCOPE_AGENT);
}
__device__ __forceinline__ unsigned long long ld_u64(const void* p) {
  return __hip_atomic_load((const unsigned long long*)p, __ATOMIC_RELAXED, __HIP_MEMORY_SCOPE_AGENT);
}
__device__ __forceinline__ void st_u32(unsigned* p, unsigned v) {
  __hip_atomic_store(p, v, __ATOMIC_RELAXED, __HIP_MEMORY_SCOPE_AGENT);
}
__device__ __forceinline__ unsigned ld_u32(const unsigned* p) {
  return __hip_atomic_load(p, __ATOMIC_RELAXED, __HIP_MEMORY_SCOPE_AGENT);
}
__device__ __forceinline__ void st_f32(float* p, float v) {
  __hip_atomic_store(p, v, __ATOMIC_RELAXED, __HIP_MEMORY_SCOPE_AGENT);
}
__device__ __forceinline__ float ld_f32(const float* p) {
  return __hip_atomic_load(p, __ATOMIC_RELAXED, __HIP_MEMORY_SCOPE_AGENT);
}
union FRAG { unsigned long long q[2]; bf16x8 v; };
__device__ __forceinline__ bf16x8 ld_frag(const short* base) {
  FRAG u;
  u.q[0] = ld_u64(base);
  u.q[1] = ld_u64(base + 4);
  return u.v;
}

// ---- sync primitives --------------------------------------------------------
__device__ __forceinline__ void setflag(unsigned* flag, unsigned val) {
  asm volatile("s_waitcnt vmcnt(0)" ::: "memory");
  __syncthreads();
  if (threadIdx.x == 0)
    __hip_atomic_store(flag, val, __ATOMIC_RELAXED, __HIP_MEMORY_SCOPE_AGENT);
}
// leader/invdone h-wait: leader polls 256 flags (64 lanes), does THE agent
// fence (L2 inv), publishes invdone. Others poll invdone, L1-inv only.
__device__ __forceinline__ void hwait(const unsigned* flags, unsigned* invdone_line,
                                      bool leader, unsigned target, int* sDead) {
  if (leader) {
    if (threadIdx.x < 64) {
      const unsigned long long* q = (const unsigned long long*)(flags + threadIdx.x * 4);
      unsigned spins = 0;
      for (;;) {
        unsigned long long q0 = ld_u64(q), q1 = ld_u64(q + 1);
        bool ok = ((unsigned)q0 >= target) && ((unsigned)(q0 >> 32) >= target)
               && ((unsigned)q1 >= target) && ((unsigned)(q1 >> 32) >= target);
        if (__all(ok)) break;
        __builtin_amdgcn_s_sleep(1);
        if (++spins > (1u << 19)) { if (threadIdx.x == 0) *sDead = 1; break; }
      }
    }
    if (threadIdx.x == 0) {
      __builtin_amdgcn_fence(__ATOMIC_ACQUIRE, "agent");   // L1+L2 inv (once/XCD)
      st_u32(invdone_line, target);
      asm volatile("s_waitcnt vmcnt(0)" ::: "memory");
    }
  } else {
    if (threadIdx.x == 0) {
      unsigned spins = 0;
      while (ld_u32(invdone_line) < target) {
        __builtin_amdgcn_s_sleep(1);
        if (++spins > (1u << 19)) { *sDead = 1; break; }
      }
      asm volatile("buffer_inv sc0" ::: "memory");          // L1-only inv
      asm volatile("s_waitcnt vmcnt(0)" ::: "memory");
    }
  }
  __syncthreads();
}
__device__ __forceinline__ void wait_hier(const unsigned* flags, unsigned* pub,
    int aggIdx, int nPub, unsigned target, int* sDead) {
  const int t = threadIdx.x;
  if (aggIdx >= 0) {
    if (t < 8) {
      const unsigned long long* q = (const unsigned long long*)(flags + aggIdx * 32 + t * 4);
      unsigned spins = 0;
      for (;;) {
        unsigned long long q0 = ld_u64(q), q1 = ld_u64(q + 1);
        bool ok = ((unsigned)q0 >= target) && ((unsigned)(q0 >> 32) >= target)
               && ((unsigned)q1 >= target) && ((unsigned)(q1 >> 32) >= target);
        if (__all(ok)) break;
        __builtin_amdgcn_s_sleep(1);
        if (++spins > (1u << 19)) { if (t == 0) *sDead = 1; break; }
      }
    }
    if (t == 0) st_u32(&pub[aggIdx], target);
  }
  if (t == 0) {
    unsigned spins = 0;
    for (;;) {
      bool ok = true;
      #pragma unroll
      for (int i = 0; i < 4; ++i) {
        if (i * 2 < nPub) {
          unsigned long long q0 = ld_u64((const unsigned long long*)pub + i);
          if (!((unsigned)q0 >= target && (unsigned)(q0 >> 32) >= target)) ok = false;
        }
      }
      if (ok) break;
      __builtin_amdgcn_s_sleep(1);
      if (++spins > (1u << 19)) { *sDead = 1; break; }
    }
  }
  __syncthreads();
}
__device__ __forceinline__ void wait64(const unsigned* flags, unsigned target, int* sDead) {
  if (threadIdx.x < 16) {
    const unsigned long long* q = (const unsigned long long*)(flags + threadIdx.x * 4);
    unsigned spins = 0;
    for (;;) {
      unsigned long long q0 = ld_u64(q), q1 = ld_u64(q + 1);
      bool ok = ((unsigned)q0 >= target) && ((unsigned)(q0 >> 32) >= target)
             && ((unsigned)q1 >= target) && ((unsigned)(q1 >> 32) >= target);
      if (__all(ok)) break;
      __builtin_amdgcn_s_sleep(1);
      if (++spins > (1u << 19)) { if (threadIdx.x == 0) *sDead = 1; break; }
    }
  }
  __syncthreads();
}

// ---- weight loaders --------------------------------------------------------
__device__ void load_gate_weights(const float* __restrict__ Wx, const float* __restrict__ Wh,
                                  int p, short* sBh, short* sBl) {
  for (int idx = threadIdx.x; idx < 24576; idx += 1024) {
    int j = idx & 7, l = (idx >> 3) & 63, kb = idx >> 9;
    int k = kb * 32 + ((l >> 4) << 3) + j;
    int c = l & 15;
    int gcol = (c >> 2) * 1024 + p * 4 + (c & 3);
    float wv = (k < 512) ? Wx[(size_t)k * 4096 + gcol]
                         : Wh[(size_t)(k - 512) * 4096 + gcol];
    short hi, lo; split2(wv, hi, lo);
    sBh[idx] = hi; sBl[idx] = lo;
  }
}
__device__ void load_fc_weights(const float* __restrict__ fcW, int kg, int cg,
                                short* sFh, short* sFl) {
  for (int idx = threadIdx.x; idx < 4096; idx += 1024) {
    int j = idx & 7, l = (idx >> 3) & 63, kb = idx >> 9;
    int unit = kg * 256 + kb * 32 + ((l >> 4) << 3) + j;
    int col = cg * 16 + (l & 15);
    short hi, lo; split2(fcW[(size_t)unit * 512 + col], hi, lo);
    sFh[idx] = hi; sFl[idx] = lo;
  }
}

// ---- gate GEMM (v9's) ------------------------------------------------------
template<int NKB, int D>
__device__ __forceinline__ void gg_pipe(const short* AH_, const short* AL_,
    const short* BH_, const short* BL_, int mt, int l,
    int kbA0, int kbB0, f32x4* acc)
{
  const bf16x8* AH = (const bf16x8*)AH_;
  const bf16x8* AL = (const bf16x8*)AL_;
  const bf16x8* BH = (const bf16x8*)BH_;
  const bf16x8* BL = (const bf16x8*)BL_;
  bf16x8 pah[D], pal[D];
  #pragma unroll
  for (int i = 0; i < D; ++i) {
    pah[i] = AH[((kbA0 + i) * 8 + mt) * 64 + l];
    pal[i] = AL[((kbA0 + i) * 8 + mt) * 64 + l];
  }
  #pragma unroll
  for (int i = 0; i < NKB; ++i) {
    bf16x8 ah = pah[i % D], al = pal[i % D];
    if (i + D < NKB) {
      pah[i % D] = AH[((kbA0 + i + D) * 8 + mt) * 64 + l];
      pal[i % D] = AL[((kbA0 + i + D) * 8 + mt) * 64 + l];
    }
    bf16x8 bh = BH[(kbB0 + i) * 64 + l];
    bf16x8 bl = BL[(kbB0 + i) * 64 + l];
    const int a = (i & 1) * 3;
    acc[a + 0] = MFMA(ah, bh, acc[a + 0], 0, 0, 0);
    acc[a + 1] = MFMA(ah, bl, acc[a + 1], 0, 0, 0);
    acc[a + 2] = MFMA(al, bh, acc[a + 2], 0, 0, 0);
  }
}
__device__ __forceinline__ void gg_finish(f32x4* acc, int kh, int mt, int l,
                                          float* LDSgate) {
  f32x4 s = (acc[0] + acc[3]) + ((acc[1] + acc[4]) + (acc[2] + acc[5]));
  const int col = l & 15, r0 = mt * 16 + ((l >> 4) << 2);
  float* plane = LDSgate + kh * 2176;
  #pragma unroll
  for (int j = 0; j < 4; ++j) plane[(r0 + j) * 17 + col] = s[j];
}

// ---- x conversion into fragment-ordered x-ring slot ------------------------
__device__ __forceinline__ void conv_x(const float* __restrict__ xsrc,
                                       short* dstH, short* dstL, int p, int tl) {
  if (tl < 32) {
    int g = p * 32 + tl;                      // 0..8191
    int l = g & 63, mt = (g >> 6) & 7, kb = g >> 9;
    int row = mt * 16 + (l & 15), k = kb * 32 + ((l >> 4) << 3);
    const float* xs = xsrc + (size_t)row * 512 + k;
    unsigned long long h64[2] = {0, 0}, l64[2] = {0, 0};
    #pragma unroll
    for (int j = 0; j < 8; ++j) {
      short hi, lo; split2(xs[j], hi, lo);
      h64[j >> 2] |= (unsigned long long)(unsigned short)hi << ((j & 3) * 16);
      l64[j >> 2] |= (unsigned long long)(unsigned short)lo << ((j & 3) * 16);
    }
    int off = g * 8;
    st_u64(dstH + off, h64[0]); st_u64(dstH + off + 4, h64[1]);
    st_u64(dstL + off, l64[0]); st_u64(dstL + off + 4, l64[1]);
  }
}

__global__ void __launch_bounds__(1024, 1)
lstm11(const float* __restrict__ x, const float* __restrict__ h0p,
       const float* __restrict__ c0p, const float* __restrict__ eWx,
       const float* __restrict__ eWh, const float* __restrict__ eb,
       const float* __restrict__ dWx, const float* __restrict__ dWh,
       const float* __restrict__ db, const float* __restrict__ fcW,
       const float* __restrict__ fcb, float* __restrict__ out,
       char* __restrict__ ws)
{
  __shared__ __align__(16) short sBh[24576], sBl[24576];   // 96 KB
  __shared__ __align__(16) short sFh[4096], sFl[4096];     // 16 KB
  __shared__ float LDSgate[2 * 2176];                      // 17.4 KB
  __shared__ unsigned hsplit[512];
  __shared__ float ybuf[512];
  __shared__ float red[16];
  __shared__ int sDead, sLeader, sXcd;

  const int p = blockIdx.x, t = threadIdx.x;
  const int w = t >> 6, l = t & 63;
  const int mt = w & 7, kh = w >> 3;
  if (t == 0) sDead = 0;

  unsigned* hflag = (unsigned*)ws;                 // 256 flags @0
  unsigned* yflag = (unsigned*)(ws + 1024);        // 128 flags
  unsigned* fflag = (unsigned*)(ws + 2048);        // 128 flags
  unsigned* ypub  = (unsigned*)(ws + 3072);        // 4 epochs
  unsigned* fpub  = (unsigned*)(ws + 3136);        // 4 epochs
  unsigned* elect = (unsigned*)(ws + 3264);        // 8 counters (one line)
  // invdone: per-XCD line at ws+3328 + xcd*64

  // ---- XCD id + one-time leader election ----
  if (t == 0) {
    unsigned xcd;
    asm volatile("s_getreg_b32 %0, hwreg(HW_REG_XCC_ID)" : "=s"(xcd));
    xcd &= 7u;
    sXcd = (int)xcd;
    unsigned old = __hip_atomic_fetch_add(&elect[xcd], 1u, __ATOMIC_ACQ_REL,
                                          __HIP_MEMORY_SCOPE_AGENT);
    sLeader = (old == 0u) ? 1 : 0;
  }
  __syncthreads();
  const bool leader = (sLeader != 0);
  unsigned* invd = (unsigned*)(ws + 3328 + sXcd * 64);

  const int yagg = (p >= 8 && p < 12) ? p - 8 : -1;
  const int fagg = (p >= 12 && p < 16) ? p - 12 : -1;

  short* xrH[4]; short* xrL[4];
  #pragma unroll
  for (int s4 = 0; s4 < 4; ++s4) {
    xrH[s4] = (short*)(ws + WS_XR + s4 * XR_SLOT);
    xrL[s4] = (short*)(ws + WS_XR + s4 * XR_SLOT + 131072u);
  }
  short* hpH[2]; short* hpL[2];
  #pragma unroll
  for (int b2 = 0; b2 < 2; ++b2) {
    hpH[b2] = (short*)(ws + WS_HP + b2 * HP_BUF);
    hpL[b2] = (short*)(ws + WS_HP + b2 * HP_BUF + 262144u);
  }
  float* fp = (float*)(ws + WS_FPN);

  const int row_pw = t & 127, u_pw = (t >> 7) & 3;

  // ================= init =================
  load_gate_weights(eWx, eWh, p, sBh, sBl);
  conv_x(x, xrH[0], xrL[0], p, t);                       // x(0)
  conv_x(x + 65536, xrH[1], xrL[1], p, t);               // x(1)
  if (t < 64) {                                          // h0 -> hp[0]
    int hg = p * 64 + t;
    int ll = hg & 63, mtt = (hg >> 6) & 7, hk = hg >> 9;
    int row = mtt * 16 + (ll & 15), k = hk * 32 + ((ll >> 4) << 3);
    const float* hs = h0p + (size_t)row * 1024 + k;
    unsigned long long h64[2] = {0, 0}, l64[2] = {0, 0};
    #pragma unroll
    for (int j = 0; j < 8; ++j) {
      short hi, lo; split2(hs[j], hi, lo);
      h64[j >> 2] |= (unsigned long long)(unsigned short)hi << ((j & 3) * 16);
      l64[j >> 2] |= (unsigned long long)(unsigned short)lo << ((j & 3) * 16);
    }
    int off = hg * 8;
    st_u64(hpH[0] + off, h64[0]); st_u64(hpH[0] + off + 4, h64[1]);
    st_u64(hpL[0] + off, l64[0]); st_u64(hpL[0] + off + 4, l64[1]);
  }
  float creg = 0.f, bq0 = 0.f, bq1 = 0.f, bq2 = 0.f, bq3 = 0.f;
  if (t < 512) {
    creg = c0p[(size_t)row_pw * 1024 + p * 4 + u_pw];
    bq0 = eb[0 * 1024 + p * 4 + u_pw];
    bq1 = eb[1 * 1024 + p * 4 + u_pw];
    bq2 = eb[2 * 1024 + p * 4 + u_pw];
    bq3 = eb[3 * 1024 + p * 4 + u_pw];
  }
  setflag(&hflag[p], 1u);
  hwait(hflag, invd, leader, 1u, &sDead);                // init barrier + inv
  if (sDead) return;

  // ================= encoder =================
  for (int st = 0; st < TS; ++st) {
    int rb = st & 1, wb = rb ^ 1, xs = st & 3;
    f32x4 z = {0.f, 0.f, 0.f, 0.f};
    f32x4 acc[6] = {z, z, z, z, z, z};
    // x-part BEFORE the wait (fresh per last step's inv; drained per flag web)
    gg_pipe<8, 4>(xrH[xs], xrL[xs], sBh, sBl, mt, l, kh * 8, kh * 8, acc);
    hwait(hflag, invd, leader, (unsigned)(st + 1), &sDead);
    if (sDead) return;
    gg_pipe<16, 4>(hpH[rb], hpL[rb], sBh, sBl, mt, l, kh * 16, 16 + kh * 16, acc);
    gg_finish(acc, kh, mt, l, LDSgate);
    __syncthreads();
    if (t < 512) {
      float g0 = LDSgate[row_pw * 17 + 0  + u_pw] + LDSgate[2176 + row_pw * 17 + 0  + u_pw] + bq0;
      float g1 = LDSgate[row_pw * 17 + 4  + u_pw] + LDSgate[2176 + row_pw * 17 + 4  + u_pw] + bq1;
      float g2 = LDSgate[row_pw * 17 + 8  + u_pw] + LDSgate[2176 + row_pw * 17 + 8  + u_pw] + bq2;
      float g3 = LDSgate[row_pw * 17 + 12 + u_pw] + LDSgate[2176 + row_pw * 17 + 12 + u_pw] + bq3;
      creg = sigm(g1) * creg + sigm(g0) * tanhfa(g2);
      float h = sigm(g3) * tanhfa(creg);
      short hi, lo; split2(h, hi, lo);
      hsplit[u_pw * 128 + row_pw] = ((unsigned)(unsigned short)hi << 16) | (unsigned short)lo;
    } else if (st + 2 < TS) {
      conv_x(x + (size_t)(st + 2) * 65536, xrH[(st + 2) & 3], xrL[(st + 2) & 3], p, t - 512);
    }
    __syncthreads();
    if (t < 128) {                                       // pack h slice (4 units)
      int r = t;
      unsigned w0 = hsplit[r], w1 = hsplit[128 + r], w2 = hsplit[256 + r], w3 = hsplit[384 + r];
      unsigned long long hi64 = (unsigned long long)(w0 >> 16)
        | ((unsigned long long)(w1 >> 16) << 16)
        | ((unsigned long long)(w2 >> 16) << 32)
        | ((unsigned long long)(w3 >> 16) << 48);
      unsigned long long lo64 = (unsigned long long)(w0 & 0xFFFFu)
        | ((unsigned long long)(w1 & 0xFFFFu) << 16)
        | ((unsigned long long)(w2 & 0xFFFFu) << 32)
        | ((unsigned long long)(w3 & 0xFFFFu) << 48);
      int hk = p >> 3, mtt = r >> 4;
      int lane_ = (((p >> 1) & 3) << 4) | (r & 15);
      int off = ((hk * 8 + mtt) * 64 + lane_) * 8 + (p & 1) * 4;
      st_u64(hpH[wb] + off, hi64);
      st_u64(hpL[wb] + off, lo64);
    }
    setflag(&hflag[p], (unsigned)(st + 2));
  }

  // ================= switch to decoder =================
  load_gate_weights(dWx, dWh, p, sBh, sBl);
  if (p >= 128) load_fc_weights(fcW, (p - 128) >> 5, (p - 128) & 31, sFh, sFl);
  if (t < 32) {                                          // zero y0 (slot 0)
    int off = (p * 32 + t) * 8;
    st_u64(xrH[0] + off, 0ull); st_u64(xrH[0] + off + 4, 0ull);
    st_u64(xrL[0] + off, 0ull); st_u64(xrL[0] + off + 4, 0ull);
  }
  creg = 0.0f;
  if (t < 512) {
    bq0 = db[0 * 1024 + p * 4 + u_pw];
    bq1 = db[1 * 1024 + p * 4 + u_pw];
    bq2 = db[2 * 1024 + p * 4 + u_pw];
    bq3 = db[3 * 1024 + p * 4 + u_pw];
  }
  float fcb_r = (t < 512) ? fcb[t] : 0.f;
  setflag(&hflag[p], (unsigned)(TS + 2));

  // ================= decoder =================
  const unsigned DB = (unsigned)(TS + 2);
  for (int st = 0; st < TS; ++st) {
    int rb = st & 1, wb = rb ^ 1;
    int ys = st & 1, yw = ys ^ 1;
    f32x4 z = {0.f, 0.f, 0.f, 0.f};
    f32x4 acc[6] = {z, z, z, z, z, z};
    hwait(hflag, invd, leader, DB + (unsigned)st, &sDead);
    if (sDead) return;
    gg_pipe<16, 4>(hpH[rb], hpL[rb], sBh, sBl, mt, l, kh * 16, 16 + kh * 16, acc);
    wait_hier(yflag, ypub, yagg, 4, (unsigned)st, &sDead);      // y(st-1), fence-free
    if (sDead) return;
    gg_pipe<8, 4>(xrH[ys], xrL[ys], sBh, sBl, mt, l, kh * 8, kh * 8, acc);
    gg_finish(acc, kh, mt, l, LDSgate);
    __syncthreads();
    if (t < 512) {
      float g0 = LDSgate[row_pw * 17 + 0  + u_pw] + LDSgate[2176 + row_pw * 17 + 0  + u_pw] + bq0;
      float g1 = LDSgate[row_pw * 17 + 4  + u_pw] + LDSgate[2176 + row_pw * 17 + 4  + u_pw] + bq1;
      float g2 = LDSgate[row_pw * 17 + 8  + u_pw] + LDSgate[2176 + row_pw * 17 + 8  + u_pw] + bq2;
      float g3 = LDSgate[row_pw * 17 + 12 + u_pw] + LDSgate[2176 + row_pw * 17 + 12 + u_pw] + bq3;
      creg = sigm(g1) * creg + sigm(g0) * tanhfa(g2);
      float h = sigm(g3) * tanhfa(creg);
      short hi, lo; split2(h, hi, lo);
      hsplit[u_pw * 128 + row_pw] = ((unsigned)(unsigned short)hi << 16) | (unsigned short)lo;
    }
    __syncthreads();
    if (t < 128) {
      int r = t;
      unsigned w0 = hsplit[r], w1 = hsplit[128 + r], w2 = hsplit[256 + r], w3 = hsplit[384 + r];
      unsigned long long hi64 = (unsigned long long)(w0 >> 16)
        | ((unsigned long long)(w1 >> 16) << 16)
        | ((unsigned long long)(w2 >> 16) << 32)
        | ((unsigned long long)(w3 >> 16) << 48);
      unsigned long long lo64 = (unsigned long long)(w0 & 0xFFFFu)
        | ((unsigned long long)(w1 & 0xFFFFu) << 16)
        | ((unsigned long long)(w2 & 0xFFFFu) << 32)
        | ((unsigned long long)(w3 & 0xFFFFu) << 48);
      int hk = p >> 3, mtt = r >> 4;
      int lane_ = (((p >> 1) & 3) << 4) | (r & 15);
      int off = ((hk * 8 + mtt) * 64 + lane_) * 8 + (p & 1) * 4;
      st_u64(hpH[wb] + off, hi64);
      st_u64(hpL[wb] + off, lo64);
    }
    setflag(&hflag[p], DB + (unsigned)(st + 1));          // h(st) ready

    if (p >= 128) {
      // ---- fc GEMM on blocks 128..255 (UC hp reads) ----
      const int f = p - 128, kg = f >> 5, cg = f & 31;
      wait64(hflag + kg * 64, DB + (unsigned)(st + 1), &sDead);
      if (sDead) return;
      {
        const bf16x8* FB = (const bf16x8*)sFh;
        const bf16x8* FL = (const bf16x8*)sFl;
        bf16x8 fah[4], fal[4];
        #pragma unroll
        for (int kb = 0; kb < 4; ++kb) {
          int gkb = kg * 8 + kh * 4 + kb;
          fah[kb] = ld_frag(hpH[wb] + ((gkb * 8 + mt) * 64 + l) * 8);
          fal[kb] = ld_frag(hpL[wb] + ((gkb * 8 + mt) * 64 + l) * 8);
        }
        f32x4 a0 = z, a1 = z, a2 = z;
        #pragma unroll
        for (int kb = 0; kb < 4; ++kb) {
          bf16x8 bh = FB[(kh * 4 + kb) * 64 + l];
          bf16x8 bl = FL[(kh * 4 + kb) * 64 + l];
          a0 = MFMA(fah[kb], bh, a0, 0, 0, 0);
          a1 = MFMA(fah[kb], bl, a1, 0, 0, 0);
          a2 = MFMA(fal[kb], bh, a2, 0, 0, 0);
        }
        f32x4 s = a0 + (a1 + a2);
        int slice = kg * 2 + kh;
        int col = cg * 16 + (l & 15), r0 = mt * 16 + ((l >> 4) << 2);
        #pragma unroll
        for (int j = 0; j < 4; ++j)
          st_f32(&fp[(size_t)(slice * 128 + r0 + j) * 512 + col], s[j]);
      }
      setflag(&fflag[f], (unsigned)(st + 1));
    } else {
      // ---- softmax + y-pack on blocks 0..127 (UC fp reads) ----
      wait_hier(fflag, fpub, fagg, 4, (unsigned)(st + 1), &sDead);
      if (sDead) return;
      float v = 0.f, e = 0.f, mx;
      if (t < 512) {
        float tv[8];
        #pragma unroll
        for (int s8 = 0; s8 < 8; ++s8)
          tv[s8] = ld_f32(&fp[(size_t)(s8 * 128 + p) * 512 + t]);
        v = fcb_r + ((tv[0] + tv[1]) + (tv[2] + tv[3]))
                  + ((tv[4] + tv[5]) + (tv[6] + tv[7]));
        mx = v;
        #pragma unroll
        for (int o = 32; o > 0; o >>= 1) mx = fmaxf(mx, __shfl_xor(mx, o));
        if (l == 0) red[w] = mx;
      }
      __syncthreads();
      if (t < 512) {
        mx = red[0];
        #pragma unroll
        for (int i = 1; i < 8; ++i) mx = fmaxf(mx, red[i]);
        e = __expf(v - mx);
        float ss = e;
        #pragma unroll
        for (int o = 32; o > 0; o >>= 1) ss += __shfl_xor(ss, o);
        if (l == 0) red[8 + w] = ss;
      }
      __syncthreads();
      if (t < 512) {
        float ss = (red[8] + red[9]) + (red[10] + red[11])
                 + (red[12] + red[13]) + (red[14] + red[15]);
        float y = e / ss;
        st_f32(&out[((size_t)st * 128 + p) * 512 + t], y);   // UC: no dirty L2
        ybuf[t] = y;
      }
      __syncthreads();
      if (t < 64) {                                      // pack y row p
        int kb = t >> 2, seg = t & 3;
        int k = kb * 32 + seg * 8;
        int lane_ = (seg << 4) | (p & 15), mtt = p >> 4;
        int off = ((kb * 8 + mtt) * 64 + lane_) * 8;
        unsigned long long h64[2] = {0, 0}, l64[2] = {0, 0};
        #pragma unroll
        for (int j = 0; j < 8; ++j) {
          short hi, lo; split2(ybuf[k + j], hi, lo);
          h64[j >> 2] |= (unsigned long long)(unsigned short)hi << ((j & 3) * 16);
          l64[j >> 2] |= (unsigned long long)(unsigned short)lo << ((j & 3) * 16);
        }
        st_u64(xrH[yw] + off, h64[0]); st_u64(xrH[yw] + off + 4, h64[1]);
        st_u64(xrL[yw] + off, l64[0]); st_u64(xrL[yw] + off + 4, l64[1]);
      }
      setflag(&yflag[p], (unsigned)(st + 1));
    }
  }
}

extern "C" void kernel_launch(void* const* d_in, const int* in_sizes, int n_in,
                              void* d_out, int out_size, void* d_ws, size_t ws_size,
                              hipStream_t stream) {
  const float* x   = (const float*)d_in[0];
  const float* h0  = (const float*)d_in[1];
  const float* c0  = (const float*)d_in[2];
  const float* eWx = (const float*)d_in[3];
  const float* eWh = (const float*)d_in[4];
  const float* eb  = (const float*)d_in[5];
  const float* dWx = (const float*)d_in[6];
  const float* dWh = (const float*)d_in[7];
  const float* db  = (const float*)d_in[8];
  const float* fcW = (const float*)d_in[9];
  const float* fcb = (const float*)d_in[10];
  float* out = (float*)d_out;

  if (ws_size < (size_t)WS_TOTAL) {
    hipMemsetAsync(d_out, 0xFF, (size_t)out_size * sizeof(float), stream);
    return;
  }
  hipMemsetAsync(d_ws, 0, 4096, stream);   // flags + pubs + elect + invdone
  hipLaunchKernelGGL(lstm11, dim3(256), dim3(1024), 0, stream,
                     x, h0, c0, eWx, eWh, eb, dWx, dWh, db, fcW, fcb, out,
                     (char*)d_ws);
}

// Round 12
// 13736.719 us; speedup vs baseline: 1.5281x; 1.1014x over previous
//
#include <hip/hip_runtime.h>

// ---------------------------------------------------------------------------
// Persistent seq2seq LSTM, v12 = v11 (leader-inv) + rebuilt decoder chain.
// Decoder: fc for step st-1 runs at iteration st right after the global
// h-wait+inv, reading h(st-1) CACHED (same lines the gate h-GEMM streams ->
// L2-shared; v11 read them UC = 16MB/step of LLC/HBM-latency loads).
// Chain per iteration: hwait -> fc -> fflag -> softmax(st-1) -> y -> yflag
// -> x-GEMM(st); h-GEMM overlaps the chain. wait64 hop deleted (h-wait
// covers fc). y/f waits are direct 128-flag polls (no aggregator leg).
// All polls busy-spin (no s_sleep). Epilogue iteration emits out[TS-1].
// Encoder identical to v11. Sync: per-block UC flag stores; per-XCD leader
// does the single agent acquire-fence (L2 inv) per step; others L1-inv only.
// ---------------------------------------------------------------------------

#define TS 384

typedef __attribute__((ext_vector_type(8))) short bf16x8;
typedef __attribute__((ext_vector_type(4))) float f32x4;

// ws layout
#define WS_XR 4096u                      // x ring: 4 slots x (hi 128KB + lo 128KB)
#define XR_SLOT 262144u
#define WS_HP (WS_XR + 4u*XR_SLOT)       // h planes: 2 bufs x (hi 256KB + lo 256KB)
#define HP_BUF 524288u
#define WS_FPN (WS_HP + 2u*HP_BUF)       // fc partials 8*128*512*4 = 2MB
#define WS_TOTAL (WS_FPN + 2097152u)

#define MFMA __builtin_amdgcn_mfma_f32_16x16x32_bf16

__device__ __forceinline__ unsigned short bf16r(float v) {
  unsigned u = __float_as_uint(v);
  u += 0x7FFFu + ((u >> 16) & 1u);
  return (unsigned short)(u >> 16);
}
__device__ __forceinline__ float bf2f(unsigned short h) {
  return __uint_as_float(((unsigned)h) << 16);
}
__device__ __forceinline__ void split2(float v, short& hi, short& lo) {
  unsigned short h = bf16r(v);
  float r = v - bf2f(h);
  hi = (short)h; lo = (short)bf16r(r);
}
__device__ __forceinline__ float sigm(float v)  { return 1.0f / (1.0f + __expf(-v)); }
__device__ __forceinline__ float tanhfa(float v){ return 1.0f - 2.0f / (__expf(2.0f*v) + 1.0f); }

__device__ __forceinline__ void st_u64(void* p, unsigned long long v) {
  __hip_atomic_store((unsigned long long*)p, v, __ATOMIC_RELAXED, __HIP_MEMORY_SCOPE_AGENT);
}
__device__ __forceinline__ unsigned long long ld_u64(const void* p) {
  return __hip_atomic_load((const unsigned long long*)p, __ATOMIC_RELAXED, __HIP_MEMORY_SCOPE_AGENT);
}
__device__ __forceinline__ void st_u32(unsigned* p, unsigned v) {
  __hip_atomic_store(p, v, __ATOMIC_RELAXED, __HIP_MEMORY_SCOPE_AGENT);
}
__device__ __forceinline__ unsigned ld_u32(const unsigned* p) {
  return __hip_atomic_load(p, __ATOMIC_RELAXED, __HIP_MEMORY_SCOPE_AGENT);
}
__device__ __forceinline__ void st_f32(float* p, float v) {
  __hip_atomic_store(p, v, __ATOMIC_RELAXED, __HIP_MEMORY_SCOPE_AGENT);
}
__device__ __forceinline__ float ld_f32(const float* p) {
  return __hip_atomic_load(p, __ATOMIC_RELAXED, __HIP_MEMORY_SCOPE_AGENT);
}

// ---- sync primitives --------------------------------------------------------
__device__ __forceinline__ void setflag(unsigned* flag, unsigned val) {
  asm volatile("s_waitcnt vmcnt(0)" ::: "memory");
  __syncthreads();
  if (threadIdx.x == 0)
    __hip_atomic_store(flag, val, __ATOMIC_RELAXED, __HIP_MEMORY_SCOPE_AGENT);
}
// leader: poll 256 flags -> THE agent fence (L2 inv) -> publish invdone.
// non-leader: poll invdone -> L1-only inv.
__device__ __forceinline__ void hwait(const unsigned* flags, unsigned* invdone_line,
                                      bool leader, unsigned target, int* sDead) {
  if (leader) {
    if (threadIdx.x < 64) {
      const unsigned long long* q = (const unsigned long long*)(flags + threadIdx.x * 4);
      unsigned spins = 0;
      for (;;) {
        unsigned long long q0 = ld_u64(q), q1 = ld_u64(q + 1);
        bool ok = ((unsigned)q0 >= target) && ((unsigned)(q0 >> 32) >= target)
               && ((unsigned)q1 >= target) && ((unsigned)(q1 >> 32) >= target);
        if (__all(ok)) break;
        if (++spins > (1u << 20)) { if (threadIdx.x == 0) *sDead = 1; break; }
      }
    }
    if (threadIdx.x == 0) {
      __builtin_amdgcn_fence(__ATOMIC_ACQUIRE, "agent");   // L1+L2 inv, once/XCD
      st_u32(invdone_line, target);
      asm volatile("s_waitcnt vmcnt(0)" ::: "memory");
    }
  } else {
    if (threadIdx.x == 0) {
      unsigned spins = 0;
      while (ld_u32(invdone_line) < target) {
        if (++spins > (1u << 20)) { *sDead = 1; break; }
      }
      asm volatile("buffer_inv sc0" ::: "memory");          // L1-only inv
      asm volatile("s_waitcnt vmcnt(0)" ::: "memory");
    }
  }
  __syncthreads();
}
// direct 128-flag poll: 32 lanes x 4 flags, busy
__device__ __forceinline__ void wait128(const unsigned* flags, unsigned target, int* sDead) {
  if (threadIdx.x < 64) {
    const int i = threadIdx.x;
    const bool act = (i * 4) < 128;
    const unsigned long long* q = (const unsigned long long*)(flags + i * 4);
    unsigned spins = 0;
    for (;;) {
      bool ok = true;
      if (act) {
        unsigned long long q0 = ld_u64(q), q1 = ld_u64(q + 1);
        ok = ((unsigned)q0 >= target) && ((unsigned)(q0 >> 32) >= target)
          && ((unsigned)q1 >= target) && ((unsigned)(q1 >> 32) >= target);
      }
      if (__all(ok)) break;
      if (++spins > (1u << 20)) { if (i == 0) *sDead = 1; break; }
    }
  }
  __syncthreads();
}

// ---- weight loaders --------------------------------------------------------
__device__ void load_gate_weights(const float* __restrict__ Wx, const float* __restrict__ Wh,
                                  int p, short* sBh, short* sBl) {
  for (int idx = threadIdx.x; idx < 24576; idx += 1024) {
    int j = idx & 7, l = (idx >> 3) & 63, kb = idx >> 9;
    int k = kb * 32 + ((l >> 4) << 3) + j;
    int c = l & 15;
    int gcol = (c >> 2) * 1024 + p * 4 + (c & 3);
    float wv = (k < 512) ? Wx[(size_t)k * 4096 + gcol]
                         : Wh[(size_t)(k - 512) * 4096 + gcol];
    short hi, lo; split2(wv, hi, lo);
    sBh[idx] = hi; sBl[idx] = lo;
  }
}
__device__ void load_fc_weights(const float* __restrict__ fcW, int kg, int cg,
                                short* sFh, short* sFl) {
  for (int idx = threadIdx.x; idx < 4096; idx += 1024) {
    int j = idx & 7, l = (idx >> 3) & 63, kb = idx >> 9;
    int unit = kg * 256 + kb * 32 + ((l >> 4) << 3) + j;
    int col = cg * 16 + (l & 15);
    short hi, lo; split2(fcW[(size_t)unit * 512 + col], hi, lo);
    sFh[idx] = hi; sFl[idx] = lo;
  }
}

// ---- gate GEMM -------------------------------------------------------------
template<int NKB, int D>
__device__ __forceinline__ void gg_pipe(const short* AH_, const short* AL_,
    const short* BH_, const short* BL_, int mt, int l,
    int kbA0, int kbB0, f32x4* acc)
{
  const bf16x8* AH = (const bf16x8*)AH_;
  const bf16x8* AL = (const bf16x8*)AL_;
  const bf16x8* BH = (const bf16x8*)BH_;
  const bf16x8* BL = (const bf16x8*)BL_;
  bf16x8 pah[D], pal[D];
  #pragma unroll
  for (int i = 0; i < D; ++i) {
    pah[i] = AH[((kbA0 + i) * 8 + mt) * 64 + l];
    pal[i] = AL[((kbA0 + i) * 8 + mt) * 64 + l];
  }
  #pragma unroll
  for (int i = 0; i < NKB; ++i) {
    bf16x8 ah = pah[i % D], al = pal[i % D];
    if (i + D < NKB) {
      pah[i % D] = AH[((kbA0 + i + D) * 8 + mt) * 64 + l];
      pal[i % D] = AL[((kbA0 + i + D) * 8 + mt) * 64 + l];
    }
    bf16x8 bh = BH[(kbB0 + i) * 64 + l];
    bf16x8 bl = BL[(kbB0 + i) * 64 + l];
    const int a = (i & 1) * 3;
    acc[a + 0] = MFMA(ah, bh, acc[a + 0], 0, 0, 0);
    acc[a + 1] = MFMA(ah, bl, acc[a + 1], 0, 0, 0);
    acc[a + 2] = MFMA(al, bh, acc[a + 2], 0, 0, 0);
  }
}
__device__ __forceinline__ void gg_finish(f32x4* acc, int kh, int mt, int l,
                                          float* LDSgate) {
  f32x4 s = (acc[0] + acc[3]) + ((acc[1] + acc[4]) + (acc[2] + acc[5]));
  const int col = l & 15, r0 = mt * 16 + ((l >> 4) << 2);
  float* plane = LDSgate + kh * 2176;
  #pragma unroll
  for (int j = 0; j < 4; ++j) plane[(r0 + j) * 17 + col] = s[j];
}

// ---- x conversion into fragment-ordered x-ring slot ------------------------
__device__ __forceinline__ void conv_x(const float* __restrict__ xsrc,
                                       short* dstH, short* dstL, int p, int tl) {
  if (tl < 32) {
    int g = p * 32 + tl;
    int l = g & 63, mt = (g >> 6) & 7, kb = g >> 9;
    int row = mt * 16 + (l & 15), k = kb * 32 + ((l >> 4) << 3);
    const float* xs = xsrc + (size_t)row * 512 + k;
    unsigned long long h64[2] = {0, 0}, l64[2] = {0, 0};
    #pragma unroll
    for (int j = 0; j < 8; ++j) {
      short hi, lo; split2(xs[j], hi, lo);
      h64[j >> 2] |= (unsigned long long)(unsigned short)hi << ((j & 3) * 16);
      l64[j >> 2] |= (unsigned long long)(unsigned short)lo << ((j & 3) * 16);
    }
    int off = g * 8;
    st_u64(dstH + off, h64[0]); st_u64(dstH + off + 4, h64[1]);
    st_u64(dstL + off, l64[0]); st_u64(dstL + off + 4, l64[1]);
  }
}

__global__ void __launch_bounds__(1024, 1)
lstm12(const float* __restrict__ x, const float* __restrict__ h0p,
       const float* __restrict__ c0p, const float* __restrict__ eWx,
       const float* __restrict__ eWh, const float* __restrict__ eb,
       const float* __restrict__ dWx, const float* __restrict__ dWh,
       const float* __restrict__ db, const float* __restrict__ fcW,
       const float* __restrict__ fcb, float* __restrict__ out,
       char* __restrict__ ws)
{
  __shared__ __align__(16) short sBh[24576], sBl[24576];   // 96 KB
  __shared__ __align__(16) short sFh[4096], sFl[4096];     // 16 KB
  __shared__ float LDSgate[2 * 2176];                      // 17.4 KB
  __shared__ unsigned hsplit[512];
  __shared__ float ybuf[512];
  __shared__ float red[16];
  __shared__ int sDead, sLeader, sXcd;

  const int p = blockIdx.x, t = threadIdx.x;
  const int w = t >> 6, l = t & 63;
  const int mt = w & 7, kh = w >> 3;
  if (t == 0) sDead = 0;

  unsigned* hflag = (unsigned*)ws;                 // 256 flags
  unsigned* yflag = (unsigned*)(ws + 1024);        // 128 flags
  unsigned* fflag = (unsigned*)(ws + 2048);        // 128 flags
  unsigned* elect = (unsigned*)(ws + 3264);        // 8 counters

  // ---- XCD id + one-time leader election ----
  if (t == 0) {
    unsigned xcd;
    asm volatile("s_getreg_b32 %0, hwreg(HW_REG_XCC_ID)" : "=s"(xcd));
    xcd &= 7u;
    sXcd = (int)xcd;
    unsigned old = __hip_atomic_fetch_add(&elect[xcd], 1u, __ATOMIC_ACQ_REL,
                                          __HIP_MEMORY_SCOPE_AGENT);
    sLeader = (old == 0u) ? 1 : 0;
  }
  __syncthreads();
  const bool leader = (sLeader != 0);
  unsigned* invd = (unsigned*)(ws + 3328 + sXcd * 64);

  short* xrH[4]; short* xrL[4];
  #pragma unroll
  for (int s4 = 0; s4 < 4; ++s4) {
    xrH[s4] = (short*)(ws + WS_XR + s4 * XR_SLOT);
    xrL[s4] = (short*)(ws + WS_XR + s4 * XR_SLOT + 131072u);
  }
  short* hpH[2]; short* hpL[2];
  #pragma unroll
  for (int b2 = 0; b2 < 2; ++b2) {
    hpH[b2] = (short*)(ws + WS_HP + b2 * HP_BUF);
    hpL[b2] = (short*)(ws + WS_HP + b2 * HP_BUF + 262144u);
  }
  float* fp = (float*)(ws + WS_FPN);

  const int row_pw = t & 127, u_pw = (t >> 7) & 3;

  // ================= init =================
  load_gate_weights(eWx, eWh, p, sBh, sBl);
  conv_x(x, xrH[0], xrL[0], p, t);                       // x(0)
  conv_x(x + 65536, xrH[1], xrL[1], p, t);               // x(1)
  if (t < 64) {                                          // h0 -> hp[0]
    int hg = p * 64 + t;
    int ll = hg & 63, mtt = (hg >> 6) & 7, hk = hg >> 9;
    int row = mtt * 16 + (ll & 15), k = hk * 32 + ((ll >> 4) << 3);
    const float* hs = h0p + (size_t)row * 1024 + k;
    unsigned long long h64[2] = {0, 0}, l64[2] = {0, 0};
    #pragma unroll
    for (int j = 0; j < 8; ++j) {
      short hi, lo; split2(hs[j], hi, lo);
      h64[j >> 2] |= (unsigned long long)(unsigned short)hi << ((j & 3) * 16);
      l64[j >> 2] |= (unsigned long long)(unsigned short)lo << ((j & 3) * 16);
    }
    int off = hg * 8;
    st_u64(hpH[0] + off, h64[0]); st_u64(hpH[0] + off + 4, h64[1]);
    st_u64(hpL[0] + off, l64[0]); st_u64(hpL[0] + off + 4, l64[1]);
  }
  float creg = 0.f, bq0 = 0.f, bq1 = 0.f, bq2 = 0.f, bq3 = 0.f;
  if (t < 512) {
    creg = c0p[(size_t)row_pw * 1024 + p * 4 + u_pw];
    bq0 = eb[0 * 1024 + p * 4 + u_pw];
    bq1 = eb[1 * 1024 + p * 4 + u_pw];
    bq2 = eb[2 * 1024 + p * 4 + u_pw];
    bq3 = eb[3 * 1024 + p * 4 + u_pw];
  }
  setflag(&hflag[p], 1u);
  hwait(hflag, invd, leader, 1u, &sDead);                // init barrier + inv
  if (sDead) return;

  // ================= encoder (identical to v11) =================
  for (int st = 0; st < TS; ++st) {
    int rb = st & 1, wb = rb ^ 1, xs = st & 3;
    f32x4 z = {0.f, 0.f, 0.f, 0.f};
    f32x4 acc[6] = {z, z, z, z, z, z};
    gg_pipe<8, 4>(xrH[xs], xrL[xs], sBh, sBl, mt, l, kh * 8, kh * 8, acc);
    hwait(hflag, invd, leader, (unsigned)(st + 1), &sDead);
    if (sDead) return;
    gg_pipe<16, 4>(hpH[rb], hpL[rb], sBh, sBl, mt, l, kh * 16, 16 + kh * 16, acc);
    gg_finish(acc, kh, mt, l, LDSgate);
    __syncthreads();
    if (t < 512) {
      float g0 = LDSgate[row_pw * 17 + 0  + u_pw] + LDSgate[2176 + row_pw * 17 + 0  + u_pw] + bq0;
      float g1 = LDSgate[row_pw * 17 + 4  + u_pw] + LDSgate[2176 + row_pw * 17 + 4  + u_pw] + bq1;
      float g2 = LDSgate[row_pw * 17 + 8  + u_pw] + LDSgate[2176 + row_pw * 17 + 8  + u_pw] + bq2;
      float g3 = LDSgate[row_pw * 17 + 12 + u_pw] + LDSgate[2176 + row_pw * 17 + 12 + u_pw] + bq3;
      creg = sigm(g1) * creg + sigm(g0) * tanhfa(g2);
      float h = sigm(g3) * tanhfa(creg);
      short hi, lo; split2(h, hi, lo);
      hsplit[u_pw * 128 + row_pw] = ((unsigned)(unsigned short)hi << 16) | (unsigned short)lo;
    } else if (st + 2 < TS) {
      conv_x(x + (size_t)(st + 2) * 65536, xrH[(st + 2) & 3], xrL[(st + 2) & 3], p, t - 512);
    }
    __syncthreads();
    if (t < 128) {
      int r = t;
      unsigned w0 = hsplit[r], w1 = hsplit[128 + r], w2 = hsplit[256 + r], w3 = hsplit[384 + r];
      unsigned long long hi64 = (unsigned long long)(w0 >> 16)
        | ((unsigned long long)(w1 >> 16) << 16)
        | ((unsigned long long)(w2 >> 16) << 32)
        | ((unsigned long long)(w3 >> 16) << 48);
      unsigned long long lo64 = (unsigned long long)(w0 & 0xFFFFu)
        | ((unsigned long long)(w1 & 0xFFFFu) << 16)
        | ((unsigned long long)(w2 & 0xFFFFu) << 32)
        | ((unsigned long long)(w3 & 0xFFFFu) << 48);
      int hk = p >> 3, mtt = r >> 4;
      int lane_ = (((p >> 1) & 3) << 4) | (r & 15);
      int off = ((hk * 8 + mtt) * 64 + lane_) * 8 + (p & 1) * 4;
      st_u64(hpH[wb] + off, hi64);
      st_u64(hpL[wb] + off, lo64);
    }
    setflag(&hflag[p], (unsigned)(st + 2));
  }

  // ================= switch to decoder =================
  load_gate_weights(dWx, dWh, p, sBh, sBl);
  if (p >= 128) load_fc_weights(fcW, (p - 128) >> 5, (p - 128) & 31, sFh, sFl);
  if (t < 32) {                                          // zero y0 (slot 0)
    int off = (p * 32 + t) * 8;
    st_u64(xrH[0] + off, 0ull); st_u64(xrH[0] + off + 4, 0ull);
    st_u64(xrL[0] + off, 0ull); st_u64(xrL[0] + off + 4, 0ull);
  }
  creg = 0.0f;
  if (t < 512) {
    bq0 = db[0 * 1024 + p * 4 + u_pw];
    bq1 = db[1 * 1024 + p * 4 + u_pw];
    bq2 = db[2 * 1024 + p * 4 + u_pw];
    bq3 = db[3 * 1024 + p * 4 + u_pw];
  }
  float fcb_r = (t < 512) ? fcb[t] : 0.f;
  setflag(&hflag[p], (unsigned)(TS + 2));

  // ================= decoder =================
  // iteration st: hwait(h(st-1)) -> [p>=128: fc(st-1) cached -> fflag]
  //   -> h-GEMM -> [p<128: fwait -> softmax(st-1) -> y-pack(slot st&1) -> yflag]
  //   -> ywait -> x-GEMM(slot st&1) -> pointwise -> hflag.
  const unsigned DB = (unsigned)(TS + 2);
  for (int st = 0; st < TS; ++st) {
    const int rb = st & 1, wb = rb ^ 1;
    f32x4 z = {0.f, 0.f, 0.f, 0.f};
    f32x4 acc[6] = {z, z, z, z, z, z};
    hwait(hflag, invd, leader, DB + (unsigned)st, &sDead);
    if (sDead) return;
    if (p >= 128) {
      const int f = p - 128, kg = f >> 5, cg = f & 31;
      if (st >= 1) {                                     // fc(h(st-1)), CACHED
        const bf16x8* AH = (const bf16x8*)hpH[rb];
        const bf16x8* AL = (const bf16x8*)hpL[rb];
        const bf16x8* FB = (const bf16x8*)sFh;
        const bf16x8* FL = (const bf16x8*)sFl;
        f32x4 a0 = z, a1 = z, a2 = z;
        #pragma unroll
        for (int kb = 0; kb < 4; ++kb) {
          int gkb = kg * 8 + kh * 4 + kb;
          bf16x8 ah = AH[(gkb * 8 + mt) * 64 + l];
          bf16x8 al = AL[(gkb * 8 + mt) * 64 + l];
          bf16x8 bh = FB[(kh * 4 + kb) * 64 + l];
          bf16x8 bl = FL[(kh * 4 + kb) * 64 + l];
          a0 = MFMA(ah, bh, a0, 0, 0, 0);
          a1 = MFMA(ah, bl, a1, 0, 0, 0);
          a2 = MFMA(al, bh, a2, 0, 0, 0);
        }
        f32x4 s = a0 + (a1 + a2);
        int slice = kg * 2 + kh;
        int col = cg * 16 + (l & 15), r0 = mt * 16 + ((l >> 4) << 2);
        #pragma unroll
        for (int j = 0; j < 4; ++j)
          st_f32(&fp[(size_t)(slice * 128 + r0 + j) * 512 + col], s[j]);
        setflag(&fflag[f], (unsigned)st);
      }
      gg_pipe<16, 4>(hpH[rb], hpL[rb], sBh, sBl, mt, l, kh * 16, 16 + kh * 16, acc);
      if (st >= 1) { wait128(yflag, (unsigned)st, &sDead); if (sDead) return; }
      gg_pipe<8, 4>(xrH[rb], xrL[rb], sBh, sBl, mt, l, kh * 8, kh * 8, acc);
    } else {
      gg_pipe<16, 4>(hpH[rb], hpL[rb], sBh, sBl, mt, l, kh * 16, 16 + kh * 16, acc);
      if (st >= 1) {
        wait128(fflag, (unsigned)st, &sDead);
        if (sDead) return;
        // softmax(st-1)
        float v = 0.f, e = 0.f, mx;
        if (t < 512) {
          float tv[8];
          #pragma unroll
          for (int s8 = 0; s8 < 8; ++s8)
            tv[s8] = ld_f32(&fp[(size_t)(s8 * 128 + p) * 512 + t]);
          v = fcb_r + ((tv[0] + tv[1]) + (tv[2] + tv[3]))
                    + ((tv[4] + tv[5]) + (tv[6] + tv[7]));
          mx = v;
          #pragma unroll
          for (int o = 32; o > 0; o >>= 1) mx = fmaxf(mx, __shfl_xor(mx, o));
          if (l == 0) red[w] = mx;
        }
        __syncthreads();
        if (t < 512) {
          mx = red[0];
          #pragma unroll
          for (int i = 1; i < 8; ++i) mx = fmaxf(mx, red[i]);
          e = __expf(v - mx);
          float ss = e;
          #pragma unroll
          for (int o = 32; o > 0; o >>= 1) ss += __shfl_xor(ss, o);
          if (l == 0) red[8 + w] = ss;
        }
        __syncthreads();
        if (t < 512) {
          float ss = (red[8] + red[9]) + (red[10] + red[11])
                   + (red[12] + red[13]) + (red[14] + red[15]);
          float y = e / ss;
          st_f32(&out[((size_t)(st - 1) * 128 + p) * 512 + t], y);
          ybuf[t] = y;
        }
        __syncthreads();
        if (t < 64) {                                    // pack y(st-1) -> slot rb
          int kb = t >> 2, seg = t & 3;
          int k = kb * 32 + seg * 8;
          int lane_ = (seg << 4) | (p & 15), mtt = p >> 4;
          int off = ((kb * 8 + mtt) * 64 + lane_) * 8;
          unsigned long long h64[2] = {0, 0}, l64[2] = {0, 0};
          #pragma unroll
          for (int j = 0; j < 8; ++j) {
            short hi, lo; split2(ybuf[k + j], hi, lo);
            h64[j >> 2] |= (unsigned long long)(unsigned short)hi << ((j & 3) * 16);
            l64[j >> 2] |= (unsigned long long)(unsigned short)lo << ((j & 3) * 16);
          }
          st_u64(xrH[rb] + off, h64[0]); st_u64(xrH[rb] + off + 4, h64[1]);
          st_u64(xrL[rb] + off, l64[0]); st_u64(xrL[rb] + off + 4, l64[1]);
        }
        setflag(&yflag[p], (unsigned)st);
        wait128(yflag, (unsigned)st, &sDead);
        if (sDead) return;
      }
      gg_pipe<8, 4>(xrH[rb], xrL[rb], sBh, sBl, mt, l, kh * 8, kh * 8, acc);
    }
    gg_finish(acc, kh, mt, l, LDSgate);
    __syncthreads();
    if (t < 512) {
      float g0 = LDSgate[row_pw * 17 + 0  + u_pw] + LDSgate[2176 + row_pw * 17 + 0  + u_pw] + bq0;
      float g1 = LDSgate[row_pw * 17 + 4  + u_pw] + LDSgate[2176 + row_pw * 17 + 4  + u_pw] + bq1;
      float g2 = LDSgate[row_pw * 17 + 8  + u_pw] + LDSgate[2176 + row_pw * 17 + 8  + u_pw] + bq2;
      float g3 = LDSgate[row_pw * 17 + 12 + u_pw] + LDSgate[2176 + row_pw * 17 + 12 + u_pw] + bq3;
      creg = sigm(g1) * creg + sigm(g0) * tanhfa(g2);
      float h = sigm(g3) * tanhfa(creg);
      short hi, lo; split2(h, hi, lo);
      hsplit[u_pw * 128 + row_pw] = ((unsigned)(unsigned short)hi << 16) | (unsigned short)lo;
    }
    __syncthreads();
    if (t < 128) {
      int r = t;
      unsigned w0 = hsplit[r], w1 = hsplit[128 + r], w2 = hsplit[256 + r], w3 = hsplit[384 + r];
      unsigned long long hi64 = (unsigned long long)(w0 >> 16)
        | ((unsigned long long)(w1 >> 16) << 16)
        | ((unsigned long long)(w2 >> 16) << 32)
        | ((unsigned long long)(w3 >> 16) << 48);
      unsigned long long lo64 = (unsigned long long)(w0 & 0xFFFFu)
        | ((unsigned long long)(w1 & 0xFFFFu) << 16)
        | ((unsigned long long)(w2 & 0xFFFFu) << 32)
        | ((unsigned long long)(w3 & 0xFFFFu) << 48);
      int hk = p >> 3, mtt = r >> 4;
      int lane_ = (((p >> 1) & 3) << 4) | (r & 15);
      int off = ((hk * 8 + mtt) * 64 + lane_) * 8 + (p & 1) * 4;
      st_u64(hpH[wb] + off, hi64);
      st_u64(hpL[wb] + off, lo64);
    }
    setflag(&hflag[p], DB + (unsigned)(st + 1));
  }

  // ================= epilogue: fc+softmax for step TS-1 =================
  {
    const int rb = TS & 1;
    hwait(hflag, invd, leader, DB + (unsigned)TS, &sDead);
    if (sDead) return;
    if (p >= 128) {
      const int f = p - 128, kg = f >> 5, cg = f & 31;
      const bf16x8* AH = (const bf16x8*)hpH[rb];
      const bf16x8* AL = (const bf16x8*)hpL[rb];
      const bf16x8* FB = (const bf16x8*)sFh;
      const bf16x8* FL = (const bf16x8*)sFl;
      f32x4 z = {0.f, 0.f, 0.f, 0.f};
      f32x4 a0 = z, a1 = z, a2 = z;
      #pragma unroll
      for (int kb = 0; kb < 4; ++kb) {
        int gkb = kg * 8 + kh * 4 + kb;
        bf16x8 ah = AH[(gkb * 8 + mt) * 64 + l];
        bf16x8 al = AL[(gkb * 8 + mt) * 64 + l];
        bf16x8 bh = FB[(kh * 4 + kb) * 64 + l];
        bf16x8 bl = FL[(kh * 4 + kb) * 64 + l];
        a0 = MFMA(ah, bh, a0, 0, 0, 0);
        a1 = MFMA(ah, bl, a1, 0, 0, 0);
        a2 = MFMA(al, bh, a2, 0, 0, 0);
      }
      f32x4 s = a0 + (a1 + a2);
      int slice = kg * 2 + kh;
      int col = cg * 16 + (l & 15), r0 = mt * 16 + ((l >> 4) << 2);
      #pragma unroll
      for (int j = 0; j < 4; ++j)
        st_f32(&fp[(size_t)(slice * 128 + r0 + j) * 512 + col], s[j]);
      setflag(&fflag[f], (unsigned)TS);
    } else {
      wait128(fflag, (unsigned)TS, &sDead);
      if (sDead) return;
      float v = 0.f, e = 0.f, mx;
      if (t < 512) {
        float tv[8];
        #pragma unroll
        for (int s8 = 0; s8 < 8; ++s8)
          tv[s8] = ld_f32(&fp[(size_t)(s8 * 128 + p) * 512 + t]);
        v = fcb_r + ((tv[0] + tv[1]) + (tv[2] + tv[3]))
                  + ((tv[4] + tv[5]) + (tv[6] + tv[7]));
        mx = v;
        #pragma unroll
        for (int o = 32; o > 0; o >>= 1) mx = fmaxf(mx, __shfl_xor(mx, o));
        if (l == 0) red[w] = mx;
      }
      __syncthreads();
      if (t < 512) {
        mx = red[0];
        #pragma unroll
        for (int i = 1; i < 8; ++i) mx = fmaxf(mx, red[i]);
        e = __expf(v - mx);
        float ss = e;
        #pragma unroll
        for (int o = 32; o > 0; o >>= 1) ss += __shfl_xor(ss, o);
        if (l == 0) red[8 + w] = ss;
      }
      __syncthreads();
      if (t < 512) {
        float ss = (red[8] + red[9]) + (red[10] + red[11])
                 + (red[12] + red[13]) + (red[14] + red[15]);
        st_f32(&out[((size_t)(TS - 1) * 128 + p) * 512 + t], e / ss);
      }
    }
  }
}

extern "C" void kernel_launch(void* const* d_in, const int* in_sizes, int n_in,
                              void* d_out, int out_size, void* d_ws, size_t ws_size,
                              hipStream_t stream) {
  const float* x   = (const float*)d_in[0];
  const float* h0  = (const float*)d_in[1];
  const float* c0  = (const float*)d_in[2];
  const float* eWx = (const float*)d_in[3];
  const float* eWh = (const float*)d_in[4];
  const float* eb  = (const float*)d_in[5];
  const float* dWx = (const float*)d_in[6];
  const float* dWh = (const float*)d_in[7];
  const float* db  = (const float*)d_in[8];
  const float* fcW = (const float*)d_in[9];
  const float* fcb = (const float*)d_in[10];
  float* out = (float*)d_out;

  if (ws_size < (size_t)WS_TOTAL) {
    hipMemsetAsync(d_out, 0xFF, (size_t)out_size * sizeof(float), stream);
    return;
  }
  hipMemsetAsync(d_ws, 0, 4096, stream);   // flags + elect + invdone
  hipLaunchKernelGGL(lstm12, dim3(256), dim3(1024), 0, stream,
                     x, h0, c0, eWx, eWh, eb, dWx, dWh, db, fcW, fcb, out,
                     (char*)d_ws);
}